// Round 21
// baseline (154.564 us; speedup 1.0000x reference)
//
#include <hip/hip_runtime.h>
#include <hip/hip_fp16.h>

#define CH 256
#define HW 4096
#define K_TOP 115
#define CAND 128
#define TPAD 152   // u16 row stride: 304B; 4-row offset = 16 mod 32 -> 2-way (free)
#define NTRI 528   // 32*33/2 upper-triangle 128x128 tiles per batch
#define NTRI_H 264 // half-triangle per XCD

typedef __attribute__((ext_vector_type(8))) short short8;
typedef __attribute__((ext_vector_type(4))) float f32x4;
typedef __attribute__((ext_vector_type(4))) unsigned int u32x4;

__device__ __forceinline__ unsigned short f32_to_bf16(float f) {
  union { float f; unsigned int u; } v; v.f = f;
  unsigned int r = v.u + 0x7fffu + ((v.u >> 16) & 1u);
  return (unsigned short)(r >> 16);
}

__device__ __forceinline__ unsigned int f16key(unsigned short h) {
  return (h & 0x8000u) ? (unsigned int)((unsigned short)~h)
                       : (unsigned int)(h | 0x8000u);
}

// stored P-form: P = key15 | 0x8000, key15 = f16key - 0x4000 (no wrap:
// |corr|<=1.008 => f16key in [0x43F0,0xBC10]); bit15 always set.
__device__ __forceinline__ unsigned int f16keyP(unsigned short h) {
  return (f16key(h) + 0x4000u) & 0xffffu;
}

__device__ __forceinline__ unsigned short key2f16(unsigned int k) {
  return (k & 0x8000u) ? (unsigned short)(k ^ 0x8000u)
                       : (unsigned short)(~k & 0xffffu);
}

// ---------- kernel 1a: rn[b][p] = 1 / max(||x[b,:,p]||, eps) ----------
__global__ void norms_kernel(const float* __restrict__ x, float* __restrict__ rn) {
  int b = blockIdx.x >> 4;
  int p = ((blockIdx.x & 15) << 8) + threadIdx.x;
  const float* xb = x + (size_t)b * CH * HW + p;
  float ss = 0.f;
  #pragma unroll 8
  for (int c = 0; c < CH; ++c) { float v = xb[(size_t)c * HW]; ss += v * v; }
  rn[b * HW + p] = 1.0f / fmaxf(sqrtf(ss), 1e-12f);
}

// ---------- kernel 1b: xnT in FRAGMENT-MAJOR layout (R14: fixes TA-bound GEMM) ----------
__global__ void transpose_kernel(const float* __restrict__ x, const float* __restrict__ rn,
                                 unsigned short* __restrict__ xnT) {
  __shared__ float tile[64][65];   // [c_local][p_local]
  int blk = blockIdx.x;
  int b = blk >> 8;
  int rem = blk & 255;
  int c0 = (rem >> 6) << 6;
  int p0 = (rem & 63) << 6;
  for (int idx = threadIdx.x; idx < 64 * 64; idx += blockDim.x) {
    int c = idx >> 6, p = idx & 63;
    tile[c][p] = x[((size_t)b * CH + c0 + c) * HW + p0 + p];
  }
  __syncthreads();
  for (int E = threadIdx.x; E < 512; E += blockDim.x) {
    int lr  = E & 15;
    int lk  = (E >> 4) & 3;
    int kkl = (E >> 6) & 1;
    int pgl = E >> 7;
    int pl = pgl * 16 + lr;
    int cl = kkl * 32 + lk * 8;
    float s = rn[b * HW + p0 + pl];
    unsigned int w0, w1, w2, w3;
    w0 = (unsigned int)f32_to_bf16(tile[cl + 0][pl] * s) |
         ((unsigned int)f32_to_bf16(tile[cl + 1][pl] * s) << 16);
    w1 = (unsigned int)f32_to_bf16(tile[cl + 2][pl] * s) |
         ((unsigned int)f32_to_bf16(tile[cl + 3][pl] * s) << 16);
    w2 = (unsigned int)f32_to_bf16(tile[cl + 4][pl] * s) |
         ((unsigned int)f32_to_bf16(tile[cl + 5][pl] * s) << 16);
    w3 = (unsigned int)f32_to_bf16(tile[cl + 6][pl] * s) |
         ((unsigned int)f32_to_bf16(tile[cl + 7][pl] * s) << 16);
    u32x4 w = {w0, w1, w2, w3};
    int pg  = (p0 >> 4) + pgl;
    int kkg = (c0 >> 5) + kkl;
    *(u32x4*)(xnT + ((((size_t)b * 256 + pg) * 8 + kkg) * 64 + lk * 16 + lr) * 8) = w;
  }
}

// ---------- kernel A: symmetric Gram -> P-form u16 keys (R15 structure) ----------
__launch_bounds__(256, 4)
__global__ void gram_kernel(const unsigned short* __restrict__ xnT,
                            unsigned short* __restrict__ gkeys, int nb) {
  __shared__ unsigned short tile[128 * TPAD];
  const int tid  = threadIdx.x;
  const int lane = tid & 63, wv = tid >> 6;
  const int wj = wv >> 1, wi = wv & 1;
  const int lr = lane & 15, lk = lane >> 4;

  int bb, t;
  if (nb == 4) {
    const int xcd = blockIdx.x & 7;
    bb = xcd >> 1;
    t  = ((xcd & 1) ? NTRI_H : 0) + (blockIdx.x >> 3);
  } else {
    bb = 0;
    t  = blockIdx.x;
  }
  int it = (int)((sqrtf(8.0f * (float)t + 1.0f) - 1.0f) * 0.5f);
  while (((it + 1) * (it + 2)) / 2 <= t) ++it;
  while ((it * (it + 1)) / 2 > t) --it;
  const int jt = t - (it * (it + 1)) / 2;  // jt <= it
  const int j0 = jt * 128, i0 = it * 128;

  const short8* x8 = (const short8*)(xnT + (size_t)bb * HW * CH);
  unsigned short* gk = gkeys + (size_t)bb * HW * HW;

  f32x4 acc[4][4];
  #pragma unroll
  for (int m = 0; m < 4; ++m)
    #pragma unroll
    for (int n = 0; n < 4; ++n) acc[m][n] = (f32x4){0.f, 0.f, 0.f, 0.f};

  const int pgj = jt * 8 + wj * 4;
  const int pgi = it * 8 + wi * 4;
  #pragma unroll
  for (int kk = 0; kk < 8; ++kk) {
    short8 af[4], bf[4];
    #pragma unroll
    for (int m = 0; m < 4; ++m)
      af[m] = x8[(size_t)((pgj + m) * 8 + kk) * 64 + lane];
    #pragma unroll
    for (int n = 0; n < 4; ++n)
      bf[n] = x8[(size_t)((pgi + n) * 8 + kk) * 64 + lane];
    #pragma unroll
    for (int m = 0; m < 4; ++m)
      #pragma unroll
      for (int n = 0; n < 4; ++n)
        acc[m][n] = __builtin_amdgcn_mfma_f32_16x16x32_bf16(af[m], bf[n],
                                                            acc[m][n], 0, 0, 0);
  }

  // phase 1: P-form keys -> tile[jloc][iloc]  (D row = j, D col = i)
  #pragma unroll
  for (int m = 0; m < 4; ++m) {
    #pragma unroll
    for (int n = 0; n < 4; ++n) {
      #pragma unroll
      for (int r = 0; r < 4; ++r) {
        int jloc = wj * 64 + m * 16 + lk * 4 + r;
        int iloc = wi * 64 + n * 16 + lr;
        tile[jloc * TPAD + iloc] =
            (unsigned short)f16keyP(__half_as_ushort(__float2half(acc[m][n][r])));
      }
    }
  }
  __syncthreads();

  // store 1: rows j of gk (coalesced 16B chunks)
  #pragma unroll
  for (int itr = 0; itr < 8; ++itr) {
    int idx = itr * 256 + tid;
    int row = idx >> 4, ch = idx & 15;
    u32x4 v = *(const u32x4*)&tile[row * TPAD + ch * 8];
    *(u32x4*)(gk + (size_t)(j0 + row) * HW + i0 + ch * 8) = v;
  }

  if (it != jt) {
    __syncthreads();  // WAR: store-1 reads done before refill
    #pragma unroll
    for (int m = 0; m < 4; ++m) {
      #pragma unroll
      for (int n = 0; n < 4; ++n) {
        int il  = wi * 64 + n * 16 + lr;
        int jl0 = wj * 64 + m * 16 + lk * 4;
        unsigned long long pk =
            (unsigned long long)f16keyP(__half_as_ushort(__float2half(acc[m][n][0]))) |
            ((unsigned long long)f16keyP(__half_as_ushort(__float2half(acc[m][n][1]))) << 16) |
            ((unsigned long long)f16keyP(__half_as_ushort(__float2half(acc[m][n][2]))) << 32) |
            ((unsigned long long)f16keyP(__half_as_ushort(__float2half(acc[m][n][3]))) << 48);
        *(unsigned long long*)&tile[il * TPAD + jl0] = pk;
      }
    }
    __syncthreads();

    // store 2: mirror rows i of gk
    #pragma unroll
    for (int itr = 0; itr < 8; ++itr) {
      int idx = itr * 256 + tid;
      int row = idx >> 4, ch = idx & 15;
      u32x4 v = *(const u32x4*)&tile[row * TPAD + ch * 8];
      *(u32x4*)(gk + (size_t)(i0 + row) * HW + j0 + ch * 8) = v;
    }
  }
}

// ---------- kernel B: top-115, 1 col/wave, ballot/mbcnt scatter, 16 waves/block ----------
// R19/R20 model: VALU-busy-bound (~84%) with the excess being OVERHEAD, not
// core counting. Cuts: (1) GATH scatter via ballot + mbcnt prefix (no LDS
// atomics, ~5 ops vs ~12); (2) 1024-thread blocks (16 waves) for higher
// waves/CU. Search math = R19's proven popcount-free SWAR.
__launch_bounds__(1024, 2)
__global__ void select_kernel(const unsigned short* __restrict__ gkeys,
                              float* __restrict__ out, int b_base, int nb) {
  __shared__ __align__(16) unsigned short cand[16][CAND];
  __shared__ unsigned int rcnt[16][CAND];
  const int tid  = threadIdx.x;
  const int lane = tid & 63, wv = tid >> 6;   // 16 waves, wave = 1 column
  int bb, cg;
  if (nb == 4) {
    const int xcd = blockIdx.x & 7;
    bb = xcd >> 1;
    cg = ((xcd & 1) << 7) + (blockIdx.x >> 3);   // [0,256) groups of 16 cols
  } else {
    bb = 0;
    cg = blockIdx.x;
  }
  const int b = b_base + bb;
  const int j = cg * 16 + wv;

  const u32x4* cp4 = (const u32x4*)(gkeys + (size_t)bb * HW * HW + (size_t)j * HW);
  u32x4 q0 = cp4[0 * 64 + lane], q1 = cp4[1 * 64 + lane];
  u32x4 q2 = cp4[2 * 64 + lane], q3 = cp4[3 * 64 + lane];
  u32x4 q4 = cp4[4 * 64 + lane], q5 = cp4[5 * 64 + lane];
  u32x4 q6 = cp4[6 * 64 + lane], q7 = cp4[7 * 64 + lane];

  unsigned int lo = 0;
  // peeled round bit=14: key15 >= 0x4000 <=> bit14 set
  {
    unsigned int S = 0;
    #define CNTB(Q) \
      S += (Q.x >> 14) & 0x00010001u; \
      S += (Q.y >> 14) & 0x00010001u; \
      S += (Q.z >> 14) & 0x00010001u; \
      S += (Q.w >> 14) & 0x00010001u;
    CNTB(q0) CNTB(q1) CNTB(q2) CNTB(q3)
    CNTB(q4) CNTB(q5) CNTB(q6) CNTB(q7)
    #undef CNTB
    int c = (int)((S & 0xffffu) + (S >> 16));
    c += __shfl_xor(c, 1);
    c += __shfl_xor(c, 2);
    c += __shfl_xor(c, 4);
    c += __shfl_xor(c, 8);
    c += __shfl_xor(c, 16);
    c += __shfl_xor(c, 32);
    if (c >= K_TOP) lo = 0x4000u;
  }
  // rounds bit 13..0 (borrow can't cross halves: P half >= 0x8000, m <= 0x7fff)
  #pragma unroll 1
  for (int bit = 13; bit >= 0; --bit) {
    const unsigned int m  = lo | (1u << bit);
    const unsigned int mm = m * 0x10001u;
    unsigned int S = 0;
    #define CNTV(Q) \
      S += ((Q.x - mm) >> 15) & 0x00010001u; \
      S += ((Q.y - mm) >> 15) & 0x00010001u; \
      S += ((Q.z - mm) >> 15) & 0x00010001u; \
      S += ((Q.w - mm) >> 15) & 0x00010001u;
    CNTV(q0) CNTV(q1) CNTV(q2) CNTV(q3)
    CNTV(q4) CNTV(q5) CNTV(q6) CNTV(q7)
    #undef CNTV
    int c = (int)((S & 0xffffu) + (S >> 16));
    c += __shfl_xor(c, 1);
    c += __shfl_xor(c, 2);
    c += __shfl_xor(c, 4);
    c += __shfl_xor(c, 8);
    c += __shfl_xor(c, 16);
    c += __shfl_xor(c, 32);
    if (c >= K_TOP) lo = m;
  }

  // prefill candidates with threshold; zero rank-offset table
  cand[wv][2 * lane]     = (unsigned short)lo;
  cand[wv][2 * lane + 1] = (unsigned short)lo;
  rcnt[wv][2 * lane]     = 0;
  rcnt[wv][2 * lane + 1] = 0;

  // scatter strictly-greater keys via ballot + mbcnt prefix (no atomics)
  int cbase = 0;
  #define GATH(v)                                                           \
    { unsigned int _v = (v);                                                \
      unsigned long long _m = __ballot(_v > lo);                            \
      int _ofs = (int)__builtin_amdgcn_mbcnt_hi(                            \
          (unsigned int)(_m >> 32),                                         \
          __builtin_amdgcn_mbcnt_lo((unsigned int)_m, 0u));                 \
      if (_v > lo) cand[wv][cbase + _ofs] = (unsigned short)_v;             \
      cbase += (int)__popcll(_m); }
  #define GATH4(Q)                                                          \
    GATH(Q.x & 0x7fffu) GATH((Q.x >> 16) & 0x7fffu)                         \
    GATH(Q.y & 0x7fffu) GATH((Q.y >> 16) & 0x7fffu)                         \
    GATH(Q.z & 0x7fffu) GATH((Q.z >> 16) & 0x7fffu)                         \
    GATH(Q.w & 0x7fffu) GATH((Q.w >> 16) & 0x7fffu)
  GATH4(q0) GATH4(q1) GATH4(q2) GATH4(q3)
  GATH4(q4) GATH4(q5) GATH4(q6) GATH4(q7)
  #undef GATH4
  #undef GATH

  __syncthreads();  // fence: scatter stores visible before u32 re-read

  // strict-greater count g per candidate (SWAR, broadcast LDS reads),
  // dense unique ranks for tie groups via atomic offsets (R15-proven).
  unsigned int k0 = cand[wv][2 * lane];
  unsigned int k1 = cand[wv][2 * lane + 1];
  const unsigned int t0 = (k0 + 1u) * 0x10001u;
  const unsigned int t1 = (k1 + 1u) * 0x10001u;
  unsigned int S0 = 0, S1 = 0;
  {
    const u32x4* cv = (const u32x4*)&cand[wv][0];
    #pragma unroll
    for (int r = 0; r < 16; ++r) {
      u32x4 p = cv[r];
      #define GC(W) { unsigned int Pt = (W) | 0x80008000u;        \
        S0 += ((Pt - t0) >> 15) & 0x00010001u;                    \
        S1 += ((Pt - t1) >> 15) & 0x00010001u; }
      GC(p.x) GC(p.y) GC(p.z) GC(p.w)
      #undef GC
    }
  }
  int g0 = (int)((S0 & 0xffffu) + (S0 >> 16));
  int g1 = (int)((S1 & 0xffffu) + (S1 >> 16));
  unsigned int o0 = atomicAdd(&rcnt[wv][g0], 1u);
  unsigned int o1 = atomicAdd(&rcnt[wv][g1], 1u);
  int r0 = g0 + (int)o0;
  int r1 = g1 + (int)o1;

  if (r0 < K_TOP)
    out[((size_t)b * K_TOP + r0) * HW + j] =
        __half2float(__ushort_as_half(key2f16(k0 + 0x4000u))) * (1.0f / 256.0f);
  if (r1 < K_TOP)
    out[((size_t)b * K_TOP + r1) * HW + j] =
        __half2float(__ushort_as_half(key2f16(k1 + 0x4000u))) * (1.0f / 256.0f);
}

extern "C" void kernel_launch(void* const* d_in, const int* in_sizes, int n_in,
                              void* d_out, int out_size, void* d_ws, size_t ws_size,
                              hipStream_t stream) {
  (void)in_sizes; (void)n_in; (void)out_size;
  const float* x = (const float*)d_in[0];
  float* out = (float*)d_out;
  float* rn = (float*)d_ws;                                       // 64 KB
  unsigned short* xnT = (unsigned short*)((char*)d_ws + 65536);   // 8 MB bf16
  const size_t GK_OFF = 65536 + (size_t)8 * 1024 * 1024;
  const size_t ONE    = (size_t)HW * HW * 2;                      // 32 MB / batch
  const size_t NEED_1 = GK_OFF + ONE;
  const size_t NEED_4 = GK_OFF + 4 * ONE;                         // 136 MB

  norms_kernel<<<64, 256, 0, stream>>>(x, rn);
  transpose_kernel<<<1024, 256, 0, stream>>>(x, rn, xnT);

  if (ws_size >= NEED_4) {
    unsigned short* gkeys = (unsigned short*)((char*)d_ws + GK_OFF);
    gram_kernel<<<4 * NTRI, 256, 0, stream>>>(xnT, gkeys, 4);
    select_kernel<<<1024, 1024, 0, stream>>>(gkeys, out, 0, 4);
  } else if (ws_size >= NEED_1) {
    unsigned short* gkeys = (unsigned short*)((char*)d_ws + GK_OFF);
    for (int b = 0; b < 4; ++b) {
      gram_kernel<<<NTRI, 256, 0, stream>>>(xnT + (size_t)b * HW * CH, gkeys, 1);
      select_kernel<<<256, 1024, 0, stream>>>(gkeys, out, b, 1);
    }
  }
}

// Round 22
// 135.103 us; speedup vs baseline: 1.1440x; 1.1440x over previous
//
#include <hip/hip_runtime.h>
#include <hip/hip_fp16.h>

#define CH 256
#define HW 4096
#define K_TOP 115
#define CAND 128
#define TPAD 152   // u16 row stride: 304B; 4-row offset = 16 mod 32 -> 2-way (free)
#define NTRI 528   // 32*33/2 upper-triangle 128x128 tiles per batch
#define NTRI_H 264 // half-triangle per XCD

typedef __attribute__((ext_vector_type(8))) short short8;
typedef __attribute__((ext_vector_type(4))) float f32x4;
typedef __attribute__((ext_vector_type(4))) unsigned int u32x4;

__device__ __forceinline__ unsigned short f32_to_bf16(float f) {
  union { float f; unsigned int u; } v; v.f = f;
  unsigned int r = v.u + 0x7fffu + ((v.u >> 16) & 1u);
  return (unsigned short)(r >> 16);
}

__device__ __forceinline__ unsigned int f16key(unsigned short h) {
  return (h & 0x8000u) ? (unsigned int)((unsigned short)~h)
                       : (unsigned int)(h | 0x8000u);
}

// stored P-form: P = key15 | 0x8000, key15 = f16key - 0x4000 (no wrap:
// |corr|<=1.008 => f16key in [0x43F0,0xBC10]); bit15 always set.
__device__ __forceinline__ unsigned int f16keyP(unsigned short h) {
  return (f16key(h) + 0x4000u) & 0xffffu;
}

__device__ __forceinline__ unsigned short key2f16(unsigned int k) {
  return (k & 0x8000u) ? (unsigned short)(k ^ 0x8000u)
                       : (unsigned short)(~k & 0xffffu);
}

// ---------- kernel 1a: rn[b][p] = 1 / max(||x[b,:,p]||, eps) ----------
__global__ void norms_kernel(const float* __restrict__ x, float* __restrict__ rn) {
  int b = blockIdx.x >> 4;
  int p = ((blockIdx.x & 15) << 8) + threadIdx.x;
  const float* xb = x + (size_t)b * CH * HW + p;
  float ss = 0.f;
  #pragma unroll 8
  for (int c = 0; c < CH; ++c) { float v = xb[(size_t)c * HW]; ss += v * v; }
  rn[b * HW + p] = 1.0f / fmaxf(sqrtf(ss), 1e-12f);
}

// ---------- kernel 1b: xnT in FRAGMENT-MAJOR layout (R14: fixes TA-bound GEMM) ----------
__global__ void transpose_kernel(const float* __restrict__ x, const float* __restrict__ rn,
                                 unsigned short* __restrict__ xnT) {
  __shared__ float tile[64][65];   // [c_local][p_local]
  int blk = blockIdx.x;
  int b = blk >> 8;
  int rem = blk & 255;
  int c0 = (rem >> 6) << 6;
  int p0 = (rem & 63) << 6;
  for (int idx = threadIdx.x; idx < 64 * 64; idx += blockDim.x) {
    int c = idx >> 6, p = idx & 63;
    tile[c][p] = x[((size_t)b * CH + c0 + c) * HW + p0 + p];
  }
  __syncthreads();
  for (int E = threadIdx.x; E < 512; E += blockDim.x) {
    int lr  = E & 15;
    int lk  = (E >> 4) & 3;
    int kkl = (E >> 6) & 1;
    int pgl = E >> 7;
    int pl = pgl * 16 + lr;
    int cl = kkl * 32 + lk * 8;
    float s = rn[b * HW + p0 + pl];
    unsigned int w0, w1, w2, w3;
    w0 = (unsigned int)f32_to_bf16(tile[cl + 0][pl] * s) |
         ((unsigned int)f32_to_bf16(tile[cl + 1][pl] * s) << 16);
    w1 = (unsigned int)f32_to_bf16(tile[cl + 2][pl] * s) |
         ((unsigned int)f32_to_bf16(tile[cl + 3][pl] * s) << 16);
    w2 = (unsigned int)f32_to_bf16(tile[cl + 4][pl] * s) |
         ((unsigned int)f32_to_bf16(tile[cl + 5][pl] * s) << 16);
    w3 = (unsigned int)f32_to_bf16(tile[cl + 6][pl] * s) |
         ((unsigned int)f32_to_bf16(tile[cl + 7][pl] * s) << 16);
    u32x4 w = {w0, w1, w2, w3};
    int pg  = (p0 >> 4) + pgl;
    int kkg = (c0 >> 5) + kkl;
    *(u32x4*)(xnT + ((((size_t)b * 256 + pg) * 8 + kkg) * 64 + lk * 16 + lr) * 8) = w;
  }
}

// ---------- kernel A: symmetric Gram -> P-form u16 keys (R15 structure) ----------
__launch_bounds__(256, 4)
__global__ void gram_kernel(const unsigned short* __restrict__ xnT,
                            unsigned short* __restrict__ gkeys, int nb) {
  __shared__ unsigned short tile[128 * TPAD];
  const int tid  = threadIdx.x;
  const int lane = tid & 63, wv = tid >> 6;
  const int wj = wv >> 1, wi = wv & 1;
  const int lr = lane & 15, lk = lane >> 4;

  int bb, t;
  if (nb == 4) {
    const int xcd = blockIdx.x & 7;
    bb = xcd >> 1;
    t  = ((xcd & 1) ? NTRI_H : 0) + (blockIdx.x >> 3);
  } else {
    bb = 0;
    t  = blockIdx.x;
  }
  int it = (int)((sqrtf(8.0f * (float)t + 1.0f) - 1.0f) * 0.5f);
  while (((it + 1) * (it + 2)) / 2 <= t) ++it;
  while ((it * (it + 1)) / 2 > t) --it;
  const int jt = t - (it * (it + 1)) / 2;  // jt <= it
  const int j0 = jt * 128, i0 = it * 128;

  const short8* x8 = (const short8*)(xnT + (size_t)bb * HW * CH);
  unsigned short* gk = gkeys + (size_t)bb * HW * HW;

  f32x4 acc[4][4];
  #pragma unroll
  for (int m = 0; m < 4; ++m)
    #pragma unroll
    for (int n = 0; n < 4; ++n) acc[m][n] = (f32x4){0.f, 0.f, 0.f, 0.f};

  const int pgj = jt * 8 + wj * 4;
  const int pgi = it * 8 + wi * 4;
  #pragma unroll
  for (int kk = 0; kk < 8; ++kk) {
    short8 af[4], bf[4];
    #pragma unroll
    for (int m = 0; m < 4; ++m)
      af[m] = x8[(size_t)((pgj + m) * 8 + kk) * 64 + lane];
    #pragma unroll
    for (int n = 0; n < 4; ++n)
      bf[n] = x8[(size_t)((pgi + n) * 8 + kk) * 64 + lane];
    #pragma unroll
    for (int m = 0; m < 4; ++m)
      #pragma unroll
      for (int n = 0; n < 4; ++n)
        acc[m][n] = __builtin_amdgcn_mfma_f32_16x16x32_bf16(af[m], bf[n],
                                                            acc[m][n], 0, 0, 0);
  }

  // phase 1: P-form keys -> tile[jloc][iloc]  (D row = j, D col = i)
  #pragma unroll
  for (int m = 0; m < 4; ++m) {
    #pragma unroll
    for (int n = 0; n < 4; ++n) {
      #pragma unroll
      for (int r = 0; r < 4; ++r) {
        int jloc = wj * 64 + m * 16 + lk * 4 + r;
        int iloc = wi * 64 + n * 16 + lr;
        tile[jloc * TPAD + iloc] =
            (unsigned short)f16keyP(__half_as_ushort(__float2half(acc[m][n][r])));
      }
    }
  }
  __syncthreads();

  // store 1: rows j of gk (coalesced 16B chunks)
  #pragma unroll
  for (int itr = 0; itr < 8; ++itr) {
    int idx = itr * 256 + tid;
    int row = idx >> 4, ch = idx & 15;
    u32x4 v = *(const u32x4*)&tile[row * TPAD + ch * 8];
    *(u32x4*)(gk + (size_t)(j0 + row) * HW + i0 + ch * 8) = v;
  }

  if (it != jt) {
    __syncthreads();  // WAR: store-1 reads done before refill
    #pragma unroll
    for (int m = 0; m < 4; ++m) {
      #pragma unroll
      for (int n = 0; n < 4; ++n) {
        int il  = wi * 64 + n * 16 + lr;
        int jl0 = wj * 64 + m * 16 + lk * 4;
        unsigned long long pk =
            (unsigned long long)f16keyP(__half_as_ushort(__float2half(acc[m][n][0]))) |
            ((unsigned long long)f16keyP(__half_as_ushort(__float2half(acc[m][n][1]))) << 16) |
            ((unsigned long long)f16keyP(__half_as_ushort(__float2half(acc[m][n][2]))) << 32) |
            ((unsigned long long)f16keyP(__half_as_ushort(__float2half(acc[m][n][3]))) << 48);
        *(unsigned long long*)&tile[il * TPAD + jl0] = pk;
      }
    }
    __syncthreads();

    // store 2: mirror rows i of gk
    #pragma unroll
    for (int itr = 0; itr < 8; ++itr) {
      int idx = itr * 256 + tid;
      int row = idx >> 4, ch = idx & 15;
      u32x4 v = *(const u32x4*)&tile[row * TPAD + ch * 8];
      *(u32x4*)(gk + (size_t)(i0 + row) * HW + j0 + ch * 8) = v;
    }
  }
}

// ---------- kernel B: per-column top-115 (R19 body) at 8 waves/EU ----------
// All select evidence (R19 +ops free / R20 fewer-waves hurt / R21 occ-drop
// hurt, conflict-cuts null) => chain-latency-bound: time ~ chain / resident
// waves. Single change vs R19: launch_bounds (256,4) -> (256,8). VGPR=40
// fits 8 waves/EU (320 <= 512); nothing else binds.
__launch_bounds__(256, 8)
__global__ void select_kernel(const unsigned short* __restrict__ gkeys,
                              float* __restrict__ out, int b_base, int nb) {
  __shared__ __align__(16) unsigned short cand[4][CAND];
  __shared__ unsigned int rcnt[4][CAND];
  __shared__ unsigned int cnt[4];
  const int tid  = threadIdx.x;
  const int lane = tid & 63, wv = tid >> 6;
  int bb, cg;
  if (nb == 4) {
    const int xcd = blockIdx.x & 7;
    bb = xcd >> 1;
    cg = ((xcd & 1) << 9) + (blockIdx.x >> 3);   // [0,1024)
  } else {
    bb = 0;
    cg = blockIdx.x;
  }
  const int b = b_base + bb;
  const int j = cg * 4 + wv;

  const u32x4* cp4 = (const u32x4*)(gkeys + (size_t)bb * HW * HW + (size_t)j * HW);
  u32x4 q0 = cp4[0 * 64 + lane], q1 = cp4[1 * 64 + lane];
  u32x4 q2 = cp4[2 * 64 + lane], q3 = cp4[3 * 64 + lane];
  u32x4 q4 = cp4[4 * 64 + lane], q5 = cp4[5 * 64 + lane];
  u32x4 q6 = cp4[6 * 64 + lane], q7 = cp4[7 * 64 + lane];

  unsigned int lo = 0;
  // peeled round bit=14: key15 >= 0x4000 <=> bit14 set (single-bit mask)
  {
    unsigned int S = 0;
    #define CNTB(Q) \
      S += (Q.x >> 14) & 0x00010001u; \
      S += (Q.y >> 14) & 0x00010001u; \
      S += (Q.z >> 14) & 0x00010001u; \
      S += (Q.w >> 14) & 0x00010001u;
    CNTB(q0) CNTB(q1) CNTB(q2) CNTB(q3)
    CNTB(q4) CNTB(q5) CNTB(q6) CNTB(q7)
    #undef CNTB
    int c = (int)((S & 0xffffu) + (S >> 16));
    c += __shfl_xor(c, 1);
    c += __shfl_xor(c, 2);
    c += __shfl_xor(c, 4);
    c += __shfl_xor(c, 8);
    c += __shfl_xor(c, 16);
    c += __shfl_xor(c, 32);
    if (c >= K_TOP) lo = 0x4000u;
  }
  // rounds bit 13..0 (borrow can't cross halves: P half >= 0x8000, m <= 0x7fff)
  #pragma unroll 1
  for (int bit = 13; bit >= 0; --bit) {
    const unsigned int m  = lo | (1u << bit);
    const unsigned int mm = m * 0x10001u;
    unsigned int S = 0;
    #define CNTV(Q) \
      S += ((Q.x - mm) >> 15) & 0x00010001u; \
      S += ((Q.y - mm) >> 15) & 0x00010001u; \
      S += ((Q.z - mm) >> 15) & 0x00010001u; \
      S += ((Q.w - mm) >> 15) & 0x00010001u;
    CNTV(q0) CNTV(q1) CNTV(q2) CNTV(q3)
    CNTV(q4) CNTV(q5) CNTV(q6) CNTV(q7)
    #undef CNTV
    int c = (int)((S & 0xffffu) + (S >> 16));
    c += __shfl_xor(c, 1);
    c += __shfl_xor(c, 2);
    c += __shfl_xor(c, 4);
    c += __shfl_xor(c, 8);
    c += __shfl_xor(c, 16);
    c += __shfl_xor(c, 32);
    if (c >= K_TOP) lo = m;
  }

  // prefill candidates with threshold; zero rank-offset table
  cand[wv][2 * lane]     = (unsigned short)lo;
  cand[wv][2 * lane + 1] = (unsigned short)lo;
  rcnt[wv][2 * lane]     = 0;
  rcnt[wv][2 * lane + 1] = 0;
  if (lane == 0) cnt[wv] = 0;

  // scatter strictly-greater 15-bit keys (<=114 guaranteed)
  #define GATH(v)                                                \
    { unsigned int _v = (v);                                     \
      if (_v > lo) {                                             \
        unsigned int _p = atomicAdd(&cnt[wv], 1u);               \
        cand[wv][_p] = (unsigned short)_v;                       \
      } }
  #define GATH4(Q)                                               \
    GATH(Q.x & 0x7fffu) GATH((Q.x >> 16) & 0x7fffu)              \
    GATH(Q.y & 0x7fffu) GATH((Q.y >> 16) & 0x7fffu)              \
    GATH(Q.z & 0x7fffu) GATH((Q.z >> 16) & 0x7fffu)              \
    GATH(Q.w & 0x7fffu) GATH((Q.w >> 16) & 0x7fffu)
  GATH4(q0) GATH4(q1) GATH4(q2) GATH4(q3)
  GATH4(q4) GATH4(q5) GATH4(q6) GATH4(q7)
  #undef GATH4
  #undef GATH

  __syncthreads();  // fence: scatter stores visible before u32 re-read

  // strict-greater count g per candidate (SWAR, broadcast LDS reads),
  // dense unique ranks for tie groups via atomic offsets.
  unsigned int k0 = cand[wv][2 * lane];
  unsigned int k1 = cand[wv][2 * lane + 1];
  const unsigned int t0 = (k0 + 1u) * 0x10001u;
  const unsigned int t1 = (k1 + 1u) * 0x10001u;
  unsigned int S0 = 0, S1 = 0;
  {
    const u32x4* cv = (const u32x4*)&cand[wv][0];
    #pragma unroll
    for (int r = 0; r < 16; ++r) {
      u32x4 p = cv[r];
      #define GC(W) { unsigned int Pt = (W) | 0x80008000u;        \
        S0 += ((Pt - t0) >> 15) & 0x00010001u;                    \
        S1 += ((Pt - t1) >> 15) & 0x00010001u; }
      GC(p.x) GC(p.y) GC(p.z) GC(p.w)
      #undef GC
    }
  }
  int g0 = (int)((S0 & 0xffffu) + (S0 >> 16));
  int g1 = (int)((S1 & 0xffffu) + (S1 >> 16));
  unsigned int o0 = atomicAdd(&rcnt[wv][g0], 1u);
  unsigned int o1 = atomicAdd(&rcnt[wv][g1], 1u);
  int r0 = g0 + (int)o0;
  int r1 = g1 + (int)o1;

  if (r0 < K_TOP)
    out[((size_t)b * K_TOP + r0) * HW + j] =
        __half2float(__ushort_as_half(key2f16(k0 + 0x4000u))) * (1.0f / 256.0f);
  if (r1 < K_TOP)
    out[((size_t)b * K_TOP + r1) * HW + j] =
        __half2float(__ushort_as_half(key2f16(k1 + 0x4000u))) * (1.0f / 256.0f);
}

extern "C" void kernel_launch(void* const* d_in, const int* in_sizes, int n_in,
                              void* d_out, int out_size, void* d_ws, size_t ws_size,
                              hipStream_t stream) {
  (void)in_sizes; (void)n_in; (void)out_size;
  const float* x = (const float*)d_in[0];
  float* out = (float*)d_out;
  float* rn = (float*)d_ws;                                       // 64 KB
  unsigned short* xnT = (unsigned short*)((char*)d_ws + 65536);   // 8 MB bf16
  const size_t GK_OFF = 65536 + (size_t)8 * 1024 * 1024;
  const size_t ONE    = (size_t)HW * HW * 2;                      // 32 MB / batch
  const size_t NEED_1 = GK_OFF + ONE;
  const size_t NEED_4 = GK_OFF + 4 * ONE;                         // 136 MB

  norms_kernel<<<64, 256, 0, stream>>>(x, rn);
  transpose_kernel<<<1024, 256, 0, stream>>>(x, rn, xnT);

  if (ws_size >= NEED_4) {
    unsigned short* gkeys = (unsigned short*)((char*)d_ws + GK_OFF);
    gram_kernel<<<4 * NTRI, 256, 0, stream>>>(xnT, gkeys, 4);
    select_kernel<<<4096, 256, 0, stream>>>(gkeys, out, 0, 4);
  } else if (ws_size >= NEED_1) {
    unsigned short* gkeys = (unsigned short*)((char*)d_ws + GK_OFF);
    for (int b = 0; b < 4; ++b) {
      gram_kernel<<<NTRI, 256, 0, stream>>>(xnT + (size_t)b * HW * CH, gkeys, 1);
      select_kernel<<<1024, 256, 0, stream>>>(gkeys, out, b, 1);
    }
  }
}